// Round 12
// baseline (287.748 us; speedup 1.0000x reference)
//
#include <hip/hip_runtime.h>

#define Hh 64
#define Ww 64
#define Cc 512
#define Bb 16
#define NTOK (1 + Hh * Ww)   // 4097
#define TW 4                 // output pixels per thread along w
#define TH 4                 // output pixels per thread along h

typedef float v2f __attribute__((ext_vector_type(2)));

// ---------------------------------------------------------------------------
// Prep kernel (unchanged): combine w7 + padded w5 + padded w3 + identity into
// one effective 7x7 kernel per channel, stored TRANSPOSED [tap][channel].
// Combine biases, copy cls tokens through.
// ---------------------------------------------------------------------------
__global__ void ppeg_prep(const float* __restrict__ w7, const float* __restrict__ b7,
                          const float* __restrict__ w5, const float* __restrict__ b5,
                          const float* __restrict__ w3, const float* __restrict__ b3,
                          const float* __restrict__ x, float* __restrict__ wt,
                          float* __restrict__ beff, float* __restrict__ out) {
    int idx = blockIdx.x * blockDim.x + threadIdx.x;
    if (idx < Cc * 49) {
        int c = idx / 49, t = idx % 49;
        int r = t / 7, s = t % 7;
        float v = w7[idx];
        if (r >= 1 && r <= 5 && s >= 1 && s <= 5) v += w5[c * 25 + (r - 1) * 5 + (s - 1)];
        if (r >= 2 && r <= 4 && s >= 2 && s <= 4) v += w3[c * 9 + (r - 2) * 3 + (s - 2)];
        if (t == 24) v += 1.0f;               // identity (center tap)
        wt[t * Cc + c] = v;                   // transposed store
    }
    if (idx < Cc) beff[idx] = b7[idx] + b5[idx] + b3[idx];
    if (idx < Bb * Cc) {
        int b = idx / Cc, c = idx % Cc;
        size_t o = (size_t)b * NTOK * Cc + c;
        out[o] = x[o];                        // cls token pass-through
    }
}

// ---------------------------------------------------------------------------
// Conv kernel v13 = v6 with TW 8->4: the first config whose per-row state
// ACTUALLY FITS the 64-VGPR allocation the compiler insists on.
//
// R11 unifying model (fits all 11 rounds within ~10%): the 14-wide input
// window never fit in registers next to the accumulator (v6 92 regs vs 64
// granted; v9 68; v12 120 vs 80; v11 106 vs 76). The allocator then
// consumes each load immediately (reusing data regs -> per-FMA-group
// vmcnt waits), serializing ~14 memory latencies PER ROW instead of one.
// Predicted times from "loads/wave x ~560cy / concurrency": v6 100 (meas
// 104), v9 139 (123), v12 95 (111), v11 ~170 (168). This is why traffic
// (203->455 MB), instr count (0.8M->2.9M) and occupancy (16->73%) all
// moved while time never did -- and why VALU duty per wave is pinned ~10%.
//
// v13: acc 4x4xv2f = 32 + window 10xv2f = 20 + addressing ~8 = ~60 <= 64.
// The whole row burst (10 loads) stays live -> loads pipeline under one
// latency, and the compiler has room to software-pipeline row k+1.
// Cost: 1.4x vmem instrs vs v6 (proven non-binding in R10/R11) and ~820 MB
// L1->L2 halo re-read (~24 us of L2 time, under target).
//
// Kept (proven): v2f channel lanes, LDS tap slab (25 KB), chunked XCD
// swizzle (regeometried: 4096 blocks % 8 == 0, group = 2 MB slab = half an
// XCD L2), nontemporal stores, 256-thread blocks, fp contract (pk_fma).
// ---------------------------------------------------------------------------
__global__ __launch_bounds__(256, 2)
void ppeg_conv(const float* __restrict__ x, const float* __restrict__ wt,
               const float* __restrict__ beff, float* __restrict__ out) {
#pragma clang fp contract(fast)
    const int tx = threadIdx.x;        // channel-pair lane 0..63
    const int ty = threadIdx.y;        // h-strip 0..3 (wave-uniform)

    // --- chunked XCD swizzle (XCD = linear id % 8, x fastest; bijective) ----
    const int L     = blockIdx.x + 64 * (blockIdx.y + 4 * blockIdx.z); // 0..4095
    const int g_lin = (L & 7) * 512 + (L >> 3);
    const int sp    = g_lin & 63;      // spatial block 0..63 within group
    const int g     = g_lin >> 6;      // 0..63 : (cblk, b) group
    const int cb    = (g & 3) * 128;
    const int b     = g >> 2;
    // ------------------------------------------------------------------------

    const int wblk  = sp & 15;         // 0..15 (w-tiles of 4)
    const int hblk  = sp >> 4;         // 0..3  (h-blocks of 16)
    const int oh0   = hblk * (TH * 4) + ty * TH;   // first of TH output rows
    const int wbase = wblk * TW;

    // Stage the block's 49x128 tap slab into LDS (once), coalesced.
    __shared__ float taps[49][128];
    const int tid = ty * 64 + tx;
    for (int idx = tid; idx < 49 * 128; idx += 256) {
        taps[idx >> 7][idx & 127] = wt[(idx >> 7) * Cc + cb + (idx & 127)];
    }
    __syncthreads();

    const int c0 = cb + 2 * tx;
    const float* xb = x + ((size_t)b * NTOK + 1) * Cc + c0;  // pixel (0,0)

    const v2f bias = *(const v2f*)&beff[c0];
    v2f acc[TH][TW];
#pragma unroll
    for (int o = 0; o < TH; ++o)
#pragma unroll
        for (int j = 0; j < TW; ++j) acc[o][j] = bias;

    const bool interior = (wblk != 0) && (wblk != 15);

    // Stream input rows ir = oh0-3 .. oh0+TH+2. Row k feeds output rows
    // o in [k-6, k] (tap row r = k-o). All indices static after unroll.
#pragma unroll
    for (int k = 0; k < TH + 6; ++k) {
        const int ir = oh0 + k - 3;
        if (ir >= 0 && ir < Hh) {              // wave-uniform (oh0 fixed/wave)
            const float* xrow = xb + (size_t)ir * (Ww * Cc);
            v2f v[TW + 6];
            if (interior) {
#pragma unroll
                for (int j = 0; j < TW + 6; ++j)
                    v[j] = *(const v2f*)(xrow + (size_t)(wbase - 3 + j) * Cc);
            } else {
#pragma unroll
                for (int j = 0; j < TW + 6; ++j) {
                    const int wc = wbase + j - 3;
                    if (wc >= 0 && wc < Ww)
                        v[j] = *(const v2f*)(xrow + (size_t)wc * Cc);
                    else {
                        v[j].x = 0.0f; v[j].y = 0.0f;
                    }
                }
            }
#pragma unroll
            for (int o = 0; o < TH; ++o) {
                if (o > k || o < k - 6) continue;   // static after unroll
                const int r = k - o;
#pragma unroll
                for (int s = 0; s < 7; ++s) {
                    const v2f tp = *(const v2f*)&taps[r * 7 + s][2 * tx];
#pragma unroll
                    for (int j = 0; j < TW; ++j)
                        acc[o][j] = tp * v[j + s] + acc[o][j];   // v_pk_fma_f32
                }
            }
        }
    }

#pragma unroll
    for (int o = 0; o < TH; ++o) {
        float* orow = out + ((size_t)b * NTOK + 1 + (size_t)(oh0 + o) * Ww + wbase) * Cc + c0;
#pragma unroll
        for (int j = 0; j < TW; ++j)
            __builtin_nontemporal_store(acc[o][j], (v2f*)(orow + (size_t)j * Cc));
    }
}

extern "C" void kernel_launch(void* const* d_in, const int* in_sizes, int n_in,
                              void* d_out, int out_size, void* d_ws, size_t ws_size,
                              hipStream_t stream) {
    const float* x  = (const float*)d_in[0];
    const float* w7 = (const float*)d_in[1];
    const float* b7 = (const float*)d_in[2];
    const float* w5 = (const float*)d_in[3];
    const float* b5 = (const float*)d_in[4];
    const float* w3 = (const float*)d_in[5];
    const float* b3 = (const float*)d_in[6];
    float* out = (float*)d_out;

    float* wt   = (float*)d_ws;          // 49*Cc floats, transposed [tap][channel]
    float* beff = wt + 49 * Cc;          // Cc floats

    ppeg_prep<<<(Cc * 49 + 255) / 256, 256, 0, stream>>>(w7, b7, w5, b5, w3, b3,
                                                         x, wt, beff, out);

    // (4 hblk x 16 wblk) x 4 cblk x 16 b = 4096 blocks of 256 threads.
    dim3 grid(64, Cc / 128, Bb);
    dim3 block(64, 4);
    ppeg_conv<<<grid, block, 0, stream>>>(x, wt, beff, out);
}